// Round 3
// baseline (131.337 us; speedup 1.0000x reference)
//
#include <hip/hip_runtime.h>

#define CIN 3
#define HH 512
#define WW 512
#define COUT 64
#define KF 48          // 3*4*4
#define HO 128
#define WO 128
#define LDA 52         // padded row stride for 48x48 matrices

#define NTAB 2048
#define YMIN (-12.0f)
#define YMAX (12.0f)
#define INVH ((float)NTAB / (YMAX - YMIN))   // 85.3333
// ws layout (floats): [0]=sigma, [1]=a=inv_sigma*INVH, [2..65]=o_c, [128..128+2*NTAB)=table(f0,df)
#define WS_TAB_OFF 128
#define WS_FLOATS (WS_TAB_OFF + 2 * NTAB)

typedef __attribute__((ext_vector_type(2))) float f32x2;

// ---------------------------------------------------------------------------
// soft-VQ as a scalar function of y (centers fixed)
// ---------------------------------------------------------------------------
__device__ __forceinline__ float vq_eval(float y, const float* __restrict__ c) {
  float d[8], m;
#pragma unroll
  for (int k = 0; k < 8; ++k) { float t = y - c[k]; d[k] = t * t; }
  m = fminf(fminf(fminf(d[0], d[1]), fminf(d[2], d[3])),
            fminf(fminf(d[4], d[5]), fminf(d[6], d[7])));
  float num = 0.f, den = 0.f;
#pragma unroll
  for (int k = 0; k < 8; ++k) {
    float e = __expf(m - d[k]);
    den += e;
    num = fmaf(c[k], e, num);
  }
  return num / den;
}

// ---------------------------------------------------------------------------
// Kernel 1: sigma (top singular value of 64x48 W) + VQ lookup table + per-
// channel affine constants.  One block, 256 threads.
//   G = W^T W;  4 squarings -> G^16;  6 matvecs -> v ~ G^96 v0;
//   Rayleigh quotient with original G -> lambda;  sigma = sqrt(lambda)
// ---------------------------------------------------------------------------
__global__ __launch_bounds__(256) void prep_sigma(
    const float* __restrict__ w, const float* __restrict__ bias,
    const float* __restrict__ centers, float* __restrict__ ws, int build_tab) {
  __shared__ float sW[COUT * KF];
  __shared__ float sG[KF * LDA];
  __shared__ float sA[KF * LDA];
  __shared__ float sB[KF * LDA];
  __shared__ float sv[64];
  __shared__ float sp[256];
  const int t = threadIdx.x;

  // ---- load W ----
  {
    const float4* w4 = (const float4*)w;
    float4* s4 = (float4*)sW;
#pragma unroll
    for (int q = 0; q < 3; ++q) s4[q * 256 + t] = w4[q * 256 + t];
  }
  __syncthreads();

  // ---- G = W^T W, 3x3 tile per thread ----
  const int ti = t >> 4, tj = t & 15;
  const int i0 = 3 * ti, j0 = 3 * tj;
  {
    float acc[3][3] = {{0.f}};
#pragma unroll 4
    for (int m = 0; m < COUT; ++m) {
      const float* wr = sW + m * KF;
      float a0 = wr[i0], a1 = wr[i0 + 1], a2 = wr[i0 + 2];
      float b0 = wr[j0], b1 = wr[j0 + 1], b2 = wr[j0 + 2];
      acc[0][0] = fmaf(a0, b0, acc[0][0]);
      acc[0][1] = fmaf(a0, b1, acc[0][1]);
      acc[0][2] = fmaf(a0, b2, acc[0][2]);
      acc[1][0] = fmaf(a1, b0, acc[1][0]);
      acc[1][1] = fmaf(a1, b1, acc[1][1]);
      acc[1][2] = fmaf(a1, b2, acc[1][2]);
      acc[2][0] = fmaf(a2, b0, acc[2][0]);
      acc[2][1] = fmaf(a2, b1, acc[2][1]);
      acc[2][2] = fmaf(a2, b2, acc[2][2]);
    }
#pragma unroll
    for (int ii = 0; ii < 3; ++ii)
#pragma unroll
      for (int jj = 0; jj < 3; ++jj) {
        sG[(i0 + ii) * LDA + j0 + jj] = acc[ii][jj];
        sA[(i0 + ii) * LDA + j0 + jj] = acc[ii][jj];
      }
  }
  __syncthreads();

  // ---- 4 squarings: sA->sB->sA->sB->sA  (G^16 ends in sA) ----
#pragma unroll 1
  for (int s = 0; s < 4; ++s) {
    const float* src = (s & 1) ? sB : sA;
    float* dst = (s & 1) ? sA : sB;
    float acc[3][3] = {{0.f}};
#pragma unroll
    for (int q = 0; q < 12; ++q) {
      float4 ar0 = *(const float4*)(src + (i0 + 0) * LDA + 4 * q);
      float4 ar1 = *(const float4*)(src + (i0 + 1) * LDA + 4 * q);
      float4 ar2 = *(const float4*)(src + (i0 + 2) * LDA + 4 * q);
      float4 br0 = *(const float4*)(src + (j0 + 0) * LDA + 4 * q);
      float4 br1 = *(const float4*)(src + (j0 + 1) * LDA + 4 * q);
      float4 br2 = *(const float4*)(src + (j0 + 2) * LDA + 4 * q);
#define DOT4(A, B, C) \
      C = fmaf(A.x, B.x, C); C = fmaf(A.y, B.y, C); \
      C = fmaf(A.z, B.z, C); C = fmaf(A.w, B.w, C);
      DOT4(ar0, br0, acc[0][0]); DOT4(ar0, br1, acc[0][1]); DOT4(ar0, br2, acc[0][2]);
      DOT4(ar1, br0, acc[1][0]); DOT4(ar1, br1, acc[1][1]); DOT4(ar1, br2, acc[1][2]);
      DOT4(ar2, br0, acc[2][0]); DOT4(ar2, br1, acc[2][1]); DOT4(ar2, br2, acc[2][2]);
#undef DOT4
    }
    __syncthreads();
#pragma unroll
    for (int ii = 0; ii < 3; ++ii)
#pragma unroll
      for (int jj = 0; jj < 3; ++jj)
        dst[(i0 + ii) * LDA + j0 + jj] = acc[ii][jj];
    __syncthreads();
  }
  const float* M = sA;   // G^16

  if (t < 64) sv[t] = (t < KF) ? 1.0f : 0.f;
  __syncthreads();

  // ---- 6 matvecs with M ----
#pragma unroll 1
  for (int it = 0; it < 6; ++it) {
    float partial = 0.f;
    if (t < 192) {
      const int row = t >> 2, seg = t & 3;
      const float* mr = M + row * LDA + seg * 12;
      const float4* v4 = (const float4*)sv;
#pragma unroll
      for (int q = 0; q < 3; ++q) {
        float4 m4 = *(const float4*)(mr + 4 * q);
        float4 vv = v4[seg * 3 + q];
        partial = fmaf(m4.x, vv.x, partial);
        partial = fmaf(m4.y, vv.y, partial);
        partial = fmaf(m4.z, vv.z, partial);
        partial = fmaf(m4.w, vv.w, partial);
      }
    }
    sp[t] = partial;
    __syncthreads();
    if (t < 64) {
      float nv = 0.f;
      if (t < KF) nv = (sp[4 * t] + sp[4 * t + 1]) + (sp[4 * t + 2] + sp[4 * t + 3]);
      float ss = nv * nv;
#pragma unroll
      for (int m = 32; m >= 1; m >>= 1) ss += __shfl_xor(ss, m, 64);
      sv[t] = (t < KF) ? nv * rsqrtf(ss) : 0.f;
    }
    __syncthreads();
  }

  // ---- Rayleigh with original G ----
  {
    float partial = 0.f;
    if (t < 192) {
      const int row = t >> 2, seg = t & 3;
      const float* mr = sG + row * LDA + seg * 12;
      const float4* v4 = (const float4*)sv;
#pragma unroll
      for (int q = 0; q < 3; ++q) {
        float4 m4 = *(const float4*)(mr + 4 * q);
        float4 vv = v4[seg * 3 + q];
        partial = fmaf(m4.x, vv.x, partial);
        partial = fmaf(m4.y, vv.y, partial);
        partial = fmaf(m4.z, vv.z, partial);
        partial = fmaf(m4.w, vv.w, partial);
      }
    }
    sp[t] = partial;
    __syncthreads();
    if (t < 64) {
      float nv = 0.f;
      if (t < KF) nv = (sp[4 * t] + sp[4 * t + 1]) + (sp[4 * t + 2] + sp[4 * t + 3]);
      float vt = sv[t];
      float num = nv * vt;
      float den = vt * vt;
#pragma unroll
      for (int m = 32; m >= 1; m >>= 1) {
        num += __shfl_xor(num, m, 64);
        den += __shfl_xor(den, m, 64);
      }
      if (t == 0) {
        float sg = sqrtf(num / den);
        ws[0] = sg;
        ws[1] = INVH / sg;
      }
    }
  }

  // ---- VQ table + per-channel offsets (independent of sigma) ----
  if (build_tab) {
    float c[8];
#pragma unroll
    for (int k = 0; k < 8; ++k) c[k] = centers[k];
    const float h = (YMAX - YMIN) / (float)NTAB;
#pragma unroll 1
    for (int k = t; k < NTAB; k += 256) {
      float y0 = YMIN + (float)k * h;
      float f0 = vq_eval(y0, c);
      float f1 = vq_eval(y0 + h, c);
      ws[WS_TAB_OFF + 2 * k]     = f0;
      ws[WS_TAB_OFF + 2 * k + 1] = f1 - f0;
    }
    if (t < COUT) ws[2 + t] = (bias[t] - YMIN) * INVH;
  }
}

// ---------------------------------------------------------------------------
// Kernel 2 (table path): strided conv + table-VQ.
// Block = 64 output positions x 4 waves; wave w handles channels [16w,16w+16).
// Weights/offsets are wave-uniform -> scalar loads.  VQ = 1 LDS lerp.
// ---------------------------------------------------------------------------
__global__ __launch_bounds__(256) void conv_vq_tab(
    const float* __restrict__ x, const float* __restrict__ w,
    const float* __restrict__ params, float* __restrict__ out) {
  __shared__ float stab[2 * NTAB];   // 16 KB: (f0, df) pairs
  const int t = threadIdx.x;

  // copy table global->LDS (1024 float4, 4 per thread)
  {
    const float4* src = (const float4*)(params + WS_TAB_OFF);
    float4* dst = (float4*)stab;
#pragma unroll
    for (int q = 0; q < 4; ++q) dst[q * 256 + t] = src[q * 256 + t];
  }
  __syncthreads();

  const int lane = t & 63;
  const int wv   = t >> 6;
  const int p    = blockIdx.x * 64 + lane;
  const int b    = p >> 14;
  const int rem  = p & 16383;
  const int i    = rem >> 7;
  const int j    = rem & 127;

  const float a_scale = params[1];   // inv_sigma * INVH (uniform)

  // load 3x4x4 patch as 12 float4 -> 24 f32x2 register pairs
  const float* xp = x + (size_t)b * (CIN * HH * WW) + (size_t)(4 * i) * WW + 4 * j;
  f32x2 p2[24];
#pragma unroll
  for (int ci = 0; ci < CIN; ++ci) {
#pragma unroll
    for (int kh = 0; kh < 4; ++kh) {
      float4 v4 = *(const float4*)(xp + (size_t)ci * (HH * WW) + kh * WW);
      p2[(ci * 4 + kh) * 2 + 0] = f32x2{v4.x, v4.y};
      p2[(ci * 4 + kh) * 2 + 1] = f32x2{v4.z, v4.w};
    }
  }

  const int c0 = wv * 16;
  float* op = out + (size_t)b * (COUT * HO * WO) + (size_t)c0 * (HO * WO) + rem;

#pragma unroll 2
  for (int cc = 0; cc < 16; ++cc) {
    const int c = c0 + cc;
    const f32x2* wr = (const f32x2*)(w + c * KF);   // uniform -> s_load
    f32x2 acc0 = {0.f, 0.f}, acc1 = {0.f, 0.f};
#pragma unroll
    for (int q = 0; q < 12; ++q) {
      acc0 = __builtin_elementwise_fma(p2[2 * q + 0], wr[2 * q + 0], acc0);
      acc1 = __builtin_elementwise_fma(p2[2 * q + 1], wr[2 * q + 1], acc1);
    }
    const float raw = (acc0.x + acc1.x) + (acc0.y + acc1.y);

    // u = (y - YMIN)/h  with y = raw*inv_sigma + bias_c   (folded constants)
    float u = fmaf(raw, a_scale, params[2 + c]);   // params[2+c] uniform
    u = fmaxf(u, 0.0f);
    u = fminf(u, (float)NTAB - 0.0005f);
    const int k = (int)u;
    const float fr = u - (float)k;
    const float2 e = ((const float2*)stab)[k];
    op[(size_t)cc * (HO * WO)] = fmaf(fr, e.y, e.x);
  }
}

// ---------------------------------------------------------------------------
// Kernel 2 (fallback, exp path) — used only if ws is too small for the table.
// ---------------------------------------------------------------------------
__global__ __launch_bounds__(256) void conv_vq_exp(
    const float* __restrict__ x, const float* __restrict__ w,
    const float* __restrict__ bias, const float* __restrict__ centers,
    const float* __restrict__ sigma_ptr, float* __restrict__ out) {
  const int t = threadIdx.x;
  const int pos = blockIdx.x * 256 + t;
  const int b   = pos >> 14;
  const int rem = pos & 16383;
  const int i   = rem >> 7;
  const int j   = rem & 127;

  const float inv_sigma = 1.0f / sigma_ptr[0];
  float cc[8], tc[8], mc2[8];
#pragma unroll
  for (int k = 0; k < 8; ++k) {
    float c = centers[k];
    cc[k] = c; tc[k] = 2.0f * c; mc2[k] = -c * c;
  }
  const float* xp = x + (size_t)b * (CIN * HH * WW) + (size_t)(4 * i) * WW + 4 * j;
  float p[KF];
#pragma unroll
  for (int ci = 0; ci < CIN; ++ci)
#pragma unroll
    for (int kh = 0; kh < 4; ++kh) {
      float4 v4 = *(const float4*)(xp + (size_t)ci * (HH * WW) + kh * WW);
      p[(ci * 4 + kh) * 4 + 0] = v4.x;
      p[(ci * 4 + kh) * 4 + 1] = v4.y;
      p[(ci * 4 + kh) * 4 + 2] = v4.z;
      p[(ci * 4 + kh) * 4 + 3] = v4.w;
    }
  float* op = out + (size_t)b * (COUT * HO * WO) + rem;
#pragma unroll 2
  for (int c = 0; c < COUT; ++c) {
    const float4* wr = (const float4*)(w + c * KF);
    float a0 = 0.f, a1 = 0.f, a2 = 0.f, a3 = 0.f;
#pragma unroll
    for (int q = 0; q < 12; ++q) {
      float4 g = wr[q];
      a0 = fmaf(p[4*q+0], g.x, a0);
      a1 = fmaf(p[4*q+1], g.y, a1);
      a2 = fmaf(p[4*q+2], g.z, a2);
      a3 = fmaf(p[4*q+3], g.w, a3);
    }
    const float y = fmaf((a0 + a1) + (a2 + a3), inv_sigma, bias[c]);
    float e0 = __expf(fmaf(tc[0], y, mc2[0])), e1 = __expf(fmaf(tc[1], y, mc2[1]));
    float e2 = __expf(fmaf(tc[2], y, mc2[2])), e3 = __expf(fmaf(tc[3], y, mc2[3]));
    float e4 = __expf(fmaf(tc[4], y, mc2[4])), e5 = __expf(fmaf(tc[5], y, mc2[5]));
    float e6 = __expf(fmaf(tc[6], y, mc2[6])), e7 = __expf(fmaf(tc[7], y, mc2[7]));
    float den = ((e0 + e1) + (e2 + e3)) + ((e4 + e5) + (e6 + e7));
    float num = (fmaf(cc[0], e0, cc[1] * e1) + fmaf(cc[2], e2, cc[3] * e3)) +
                (fmaf(cc[4], e4, cc[5] * e5) + fmaf(cc[6], e6, cc[7] * e7));
    op[(size_t)c * (HO * WO)] = __fdividef(num, den);
  }
}

extern "C" void kernel_launch(void* const* d_in, const int* in_sizes, int n_in,
                              void* d_out, int out_size, void* d_ws, size_t ws_size,
                              hipStream_t stream) {
  const float* x       = (const float*)d_in[0];
  const float* w       = (const float*)d_in[1];
  const float* b       = (const float*)d_in[2];
  const float* centers = (const float*)d_in[3];
  float* out = (float*)d_out;
  float* ws  = (float*)d_ws;

  const int use_table = (ws_size >= (size_t)WS_FLOATS * sizeof(float)) ? 1 : 0;

  prep_sigma<<<1, 256, 0, stream>>>(w, b, centers, ws, use_table);
  if (use_table)
    conv_vq_tab<<<(16 * HO * WO) / 64, 256, 0, stream>>>(x, w, ws, out);
  else
    conv_vq_exp<<<(16 * HO * WO) / 256, 256, 0, stream>>>(x, w, b, centers, ws, out);
}

// Round 4
// 81.985 us; speedup vs baseline: 1.6020x; 1.6020x over previous
//
#include <hip/hip_runtime.h>

#define CIN 3
#define HH 512
#define WW 512
#define COUT 64
#define KF 48          // 3*4*4
#define HO 128
#define WO 128
#define LDA 52         // padded row stride for 48x48 matrices

#define NTAB 2048
#define YMIN (-12.0f)
#define YMAX (12.0f)
#define INVH ((float)NTAB / (YMAX - YMIN))   // 85.3333
// ws layout (floats): [0]=sigma, [1]=a=inv_sigma*INVH, [2..65]=o_c, [128..128+2*NTAB)=table(f0,df)
#define WS_TAB_OFF 128
#define WS_FLOATS (WS_TAB_OFF + 2 * NTAB)

// ---------------------------------------------------------------------------
// soft-VQ as a scalar function of y (centers fixed)
// ---------------------------------------------------------------------------
__device__ __forceinline__ float vq_eval(float y, const float* __restrict__ c) {
  float d[8], m;
#pragma unroll
  for (int k = 0; k < 8; ++k) { float t = y - c[k]; d[k] = t * t; }
  m = fminf(fminf(fminf(d[0], d[1]), fminf(d[2], d[3])),
            fminf(fminf(d[4], d[5]), fminf(d[6], d[7])));
  float num = 0.f, den = 0.f;
#pragma unroll
  for (int k = 0; k < 8; ++k) {
    float e = __expf(m - d[k]);
    den += e;
    num = fmaf(c[k], e, num);
  }
  return num / den;
}

// ---------------------------------------------------------------------------
// Kernel 1: sigma (top singular value of 64x48 W) + VQ lookup table + per-
// channel affine constants.  One block, 256 threads.
//   G = W^T W;  4 squarings -> G^16;  6 matvecs -> v ~ G^96 v0;
//   Rayleigh quotient with original G -> lambda;  sigma = sqrt(lambda)
// ---------------------------------------------------------------------------
__global__ __launch_bounds__(256) void prep_sigma(
    const float* __restrict__ w, const float* __restrict__ bias,
    const float* __restrict__ centers, float* __restrict__ ws, int build_tab) {
  __shared__ float sW[COUT * KF];
  __shared__ float sG[KF * LDA];
  __shared__ float sA[KF * LDA];
  __shared__ float sB[KF * LDA];
  __shared__ float sv[64];
  __shared__ float sp[256];
  const int t = threadIdx.x;

  // ---- load W ----
  {
    const float4* w4 = (const float4*)w;
    float4* s4 = (float4*)sW;
#pragma unroll
    for (int q = 0; q < 3; ++q) s4[q * 256 + t] = w4[q * 256 + t];
  }
  __syncthreads();

  // ---- G = W^T W, 3x3 tile per thread ----
  const int ti = t >> 4, tj = t & 15;
  const int i0 = 3 * ti, j0 = 3 * tj;
  {
    float acc[3][3] = {{0.f}};
#pragma unroll 4
    for (int m = 0; m < COUT; ++m) {
      const float* wr = sW + m * KF;
      float a0 = wr[i0], a1 = wr[i0 + 1], a2 = wr[i0 + 2];
      float b0 = wr[j0], b1 = wr[j0 + 1], b2 = wr[j0 + 2];
      acc[0][0] = fmaf(a0, b0, acc[0][0]);
      acc[0][1] = fmaf(a0, b1, acc[0][1]);
      acc[0][2] = fmaf(a0, b2, acc[0][2]);
      acc[1][0] = fmaf(a1, b0, acc[1][0]);
      acc[1][1] = fmaf(a1, b1, acc[1][1]);
      acc[1][2] = fmaf(a1, b2, acc[1][2]);
      acc[2][0] = fmaf(a2, b0, acc[2][0]);
      acc[2][1] = fmaf(a2, b1, acc[2][1]);
      acc[2][2] = fmaf(a2, b2, acc[2][2]);
    }
#pragma unroll
    for (int ii = 0; ii < 3; ++ii)
#pragma unroll
      for (int jj = 0; jj < 3; ++jj) {
        sG[(i0 + ii) * LDA + j0 + jj] = acc[ii][jj];
        sA[(i0 + ii) * LDA + j0 + jj] = acc[ii][jj];
      }
  }
  __syncthreads();

  // ---- 4 squarings: sA->sB->sA->sB->sA  (G^16 ends in sA) ----
#pragma unroll 1
  for (int s = 0; s < 4; ++s) {
    const float* src = (s & 1) ? sB : sA;
    float* dst = (s & 1) ? sA : sB;
    float acc[3][3] = {{0.f}};
#pragma unroll
    for (int q = 0; q < 12; ++q) {
      float4 ar0 = *(const float4*)(src + (i0 + 0) * LDA + 4 * q);
      float4 ar1 = *(const float4*)(src + (i0 + 1) * LDA + 4 * q);
      float4 ar2 = *(const float4*)(src + (i0 + 2) * LDA + 4 * q);
      float4 br0 = *(const float4*)(src + (j0 + 0) * LDA + 4 * q);
      float4 br1 = *(const float4*)(src + (j0 + 1) * LDA + 4 * q);
      float4 br2 = *(const float4*)(src + (j0 + 2) * LDA + 4 * q);
#define DOT4(A, B, C) \
      C = fmaf(A.x, B.x, C); C = fmaf(A.y, B.y, C); \
      C = fmaf(A.z, B.z, C); C = fmaf(A.w, B.w, C);
      DOT4(ar0, br0, acc[0][0]); DOT4(ar0, br1, acc[0][1]); DOT4(ar0, br2, acc[0][2]);
      DOT4(ar1, br0, acc[1][0]); DOT4(ar1, br1, acc[1][1]); DOT4(ar1, br2, acc[1][2]);
      DOT4(ar2, br0, acc[2][0]); DOT4(ar2, br1, acc[2][1]); DOT4(ar2, br2, acc[2][2]);
#undef DOT4
    }
    __syncthreads();
#pragma unroll
    for (int ii = 0; ii < 3; ++ii)
#pragma unroll
      for (int jj = 0; jj < 3; ++jj)
        dst[(i0 + ii) * LDA + j0 + jj] = acc[ii][jj];
    __syncthreads();
  }
  const float* M = sA;   // G^16

  if (t < 64) sv[t] = (t < KF) ? 1.0f : 0.f;
  __syncthreads();

  // ---- 6 matvecs with M ----
#pragma unroll 1
  for (int it = 0; it < 6; ++it) {
    float partial = 0.f;
    if (t < 192) {
      const int row = t >> 2, seg = t & 3;
      const float* mr = M + row * LDA + seg * 12;
      const float4* v4 = (const float4*)sv;
#pragma unroll
      for (int q = 0; q < 3; ++q) {
        float4 m4 = *(const float4*)(mr + 4 * q);
        float4 vv = v4[seg * 3 + q];
        partial = fmaf(m4.x, vv.x, partial);
        partial = fmaf(m4.y, vv.y, partial);
        partial = fmaf(m4.z, vv.z, partial);
        partial = fmaf(m4.w, vv.w, partial);
      }
    }
    sp[t] = partial;
    __syncthreads();
    if (t < 64) {
      float nv = 0.f;
      if (t < KF) nv = (sp[4 * t] + sp[4 * t + 1]) + (sp[4 * t + 2] + sp[4 * t + 3]);
      float ss = nv * nv;
#pragma unroll
      for (int m = 32; m >= 1; m >>= 1) ss += __shfl_xor(ss, m, 64);
      sv[t] = (t < KF) ? nv * rsqrtf(ss) : 0.f;
    }
    __syncthreads();
  }

  // ---- Rayleigh with original G ----
  {
    float partial = 0.f;
    if (t < 192) {
      const int row = t >> 2, seg = t & 3;
      const float* mr = sG + row * LDA + seg * 12;
      const float4* v4 = (const float4*)sv;
#pragma unroll
      for (int q = 0; q < 3; ++q) {
        float4 m4 = *(const float4*)(mr + 4 * q);
        float4 vv = v4[seg * 3 + q];
        partial = fmaf(m4.x, vv.x, partial);
        partial = fmaf(m4.y, vv.y, partial);
        partial = fmaf(m4.z, vv.z, partial);
        partial = fmaf(m4.w, vv.w, partial);
      }
    }
    sp[t] = partial;
    __syncthreads();
    if (t < 64) {
      float nv = 0.f;
      if (t < KF) nv = (sp[4 * t] + sp[4 * t + 1]) + (sp[4 * t + 2] + sp[4 * t + 3]);
      float vt = sv[t];
      float num = nv * vt;
      float den = vt * vt;
#pragma unroll
      for (int m = 32; m >= 1; m >>= 1) {
        num += __shfl_xor(num, m, 64);
        den += __shfl_xor(den, m, 64);
      }
      if (t == 0) {
        float sg = sqrtf(num / den);
        ws[0] = sg;
        ws[1] = INVH / sg;
      }
    }
  }

  // ---- VQ table + per-channel offsets (independent of sigma) ----
  if (build_tab) {
    float c[8];
#pragma unroll
    for (int k = 0; k < 8; ++k) c[k] = centers[k];
    const float h = (YMAX - YMIN) / (float)NTAB;
#pragma unroll 1
    for (int k = t; k < NTAB; k += 256) {
      float y0 = YMIN + (float)k * h;
      float f0 = vq_eval(y0, c);
      float f1 = vq_eval(y0 + h, c);
      ws[WS_TAB_OFF + 2 * k]     = f0;
      ws[WS_TAB_OFF + 2 * k + 1] = f1 - f0;
    }
    if (t < COUT) ws[2 + t] = (bias[t] - YMIN) * INVH;
  }
}

// ---------------------------------------------------------------------------
// Kernel 2 (table path): strided conv + table-VQ.
// Round-2 structure (thread <-> output position, scalar-load weights) + LDS
// table lerp for the VQ.  Channels split across 2 blocks (0-31 / 32-63) so
// grid = 2048 blocks = 8 blocks/CU -> full wave occupancy for latency hiding.
// ---------------------------------------------------------------------------
__global__ __launch_bounds__(256) void conv_vq_tab2(
    const float* __restrict__ x, const float* __restrict__ w,
    const float* __restrict__ params, float* __restrict__ out) {
  __shared__ float stab[2 * NTAB];   // 16 KB: (f0, df) pairs
  const int t = threadIdx.x;

  // copy table global->LDS (1024 float4, 4 per thread; L2-hot after block 0)
  {
    const float4* src = (const float4*)(params + WS_TAB_OFF);
    float4* dst = (float4*)stab;
#pragma unroll
    for (int q = 0; q < 4; ++q) dst[q * 256 + t] = src[q * 256 + t];
  }
  __syncthreads();

  const int bid = blockIdx.x;
  const int ch0 = (bid & 1) * 32;            // channel half
  const int pos = (bid >> 1) * 256 + t;      // 16*128*128 = 262144 total
  const int b   = pos >> 14;
  const int rem = pos & 16383;
  const int i   = rem >> 7;
  const int j   = rem & 127;

  const float a_scale = params[1];   // inv_sigma * INVH (uniform -> scalar)

  // load 3x4x4 input patch as 12 float4 (coalesced: lane j -> 16B stride)
  const float* xp = x + (size_t)b * (CIN * HH * WW) + (size_t)(4 * i) * WW + 4 * j;
  float p[KF];
#pragma unroll
  for (int ci = 0; ci < CIN; ++ci) {
#pragma unroll
    for (int kh = 0; kh < 4; ++kh) {
      float4 v4 = *(const float4*)(xp + (size_t)ci * (HH * WW) + kh * WW);
      p[(ci * 4 + kh) * 4 + 0] = v4.x;
      p[(ci * 4 + kh) * 4 + 1] = v4.y;
      p[(ci * 4 + kh) * 4 + 2] = v4.z;
      p[(ci * 4 + kh) * 4 + 3] = v4.w;
    }
  }

  float* op = out + (size_t)b * (COUT * HO * WO) + (size_t)ch0 * (HO * WO) + rem;
  const float2* tab2 = (const float2*)stab;

#pragma unroll 2
  for (int cc = 0; cc < 32; ++cc) {
    const int c = ch0 + cc;
    const float4* wr = (const float4*)(w + c * KF);   // uniform -> s_load
    float a0 = 0.f, a1 = 0.f, a2 = 0.f, a3 = 0.f;
#pragma unroll
    for (int q = 0; q < 12; ++q) {
      float4 g = wr[q];
      a0 = fmaf(p[4*q+0], g.x, a0);
      a1 = fmaf(p[4*q+1], g.y, a1);
      a2 = fmaf(p[4*q+2], g.z, a2);
      a3 = fmaf(p[4*q+3], g.w, a3);
    }
    const float raw = (a0 + a1) + (a2 + a3);

    // u = (y - YMIN)/h  with y = raw*inv_sigma + bias_c   (folded constants)
    float u = fmaf(raw, a_scale, params[2 + c]);      // params[2+c] uniform
    u = fmaxf(u, 0.0f);
    u = fminf(u, (float)NTAB - 0.0005f);
    const int k = (int)u;
    const float fr = u - (float)k;
    const float2 e = tab2[k];
    op[(size_t)cc * (HO * WO)] = fmaf(fr, e.y, e.x);
  }
}

// ---------------------------------------------------------------------------
// Kernel 2 (fallback, exp path) — used only if ws is too small for the table.
// ---------------------------------------------------------------------------
__global__ __launch_bounds__(256) void conv_vq_exp(
    const float* __restrict__ x, const float* __restrict__ w,
    const float* __restrict__ bias, const float* __restrict__ centers,
    const float* __restrict__ sigma_ptr, float* __restrict__ out) {
  const int t = threadIdx.x;
  const int pos = blockIdx.x * 256 + t;
  const int b   = pos >> 14;
  const int rem = pos & 16383;
  const int i   = rem >> 7;
  const int j   = rem & 127;

  const float inv_sigma = 1.0f / sigma_ptr[0];
  float cc[8], tc[8], mc2[8];
#pragma unroll
  for (int k = 0; k < 8; ++k) {
    float c = centers[k];
    cc[k] = c; tc[k] = 2.0f * c; mc2[k] = -c * c;
  }
  const float* xp = x + (size_t)b * (CIN * HH * WW) + (size_t)(4 * i) * WW + 4 * j;
  float p[KF];
#pragma unroll
  for (int ci = 0; ci < CIN; ++ci)
#pragma unroll
    for (int kh = 0; kh < 4; ++kh) {
      float4 v4 = *(const float4*)(xp + (size_t)ci * (HH * WW) + kh * WW);
      p[(ci * 4 + kh) * 4 + 0] = v4.x;
      p[(ci * 4 + kh) * 4 + 1] = v4.y;
      p[(ci * 4 + kh) * 4 + 2] = v4.z;
      p[(ci * 4 + kh) * 4 + 3] = v4.w;
    }
  float* op = out + (size_t)b * (COUT * HO * WO) + rem;
#pragma unroll 2
  for (int c = 0; c < COUT; ++c) {
    const float4* wr = (const float4*)(w + c * KF);
    float a0 = 0.f, a1 = 0.f, a2 = 0.f, a3 = 0.f;
#pragma unroll
    for (int q = 0; q < 12; ++q) {
      float4 g = wr[q];
      a0 = fmaf(p[4*q+0], g.x, a0);
      a1 = fmaf(p[4*q+1], g.y, a1);
      a2 = fmaf(p[4*q+2], g.z, a2);
      a3 = fmaf(p[4*q+3], g.w, a3);
    }
    const float y = fmaf((a0 + a1) + (a2 + a3), inv_sigma, bias[c]);
    float e0 = __expf(fmaf(tc[0], y, mc2[0])), e1 = __expf(fmaf(tc[1], y, mc2[1]));
    float e2 = __expf(fmaf(tc[2], y, mc2[2])), e3 = __expf(fmaf(tc[3], y, mc2[3]));
    float e4 = __expf(fmaf(tc[4], y, mc2[4])), e5 = __expf(fmaf(tc[5], y, mc2[5]));
    float e6 = __expf(fmaf(tc[6], y, mc2[6])), e7 = __expf(fmaf(tc[7], y, mc2[7]));
    float den = ((e0 + e1) + (e2 + e3)) + ((e4 + e5) + (e6 + e7));
    float num = (fmaf(cc[0], e0, cc[1] * e1) + fmaf(cc[2], e2, cc[3] * e3)) +
                (fmaf(cc[4], e4, cc[5] * e5) + fmaf(cc[6], e6, cc[7] * e7));
    op[(size_t)c * (HO * WO)] = __fdividef(num, den);
  }
}

extern "C" void kernel_launch(void* const* d_in, const int* in_sizes, int n_in,
                              void* d_out, int out_size, void* d_ws, size_t ws_size,
                              hipStream_t stream) {
  const float* x       = (const float*)d_in[0];
  const float* w       = (const float*)d_in[1];
  const float* b       = (const float*)d_in[2];
  const float* centers = (const float*)d_in[3];
  float* out = (float*)d_out;
  float* ws  = (float*)d_ws;

  const int use_table = (ws_size >= (size_t)WS_FLOATS * sizeof(float)) ? 1 : 0;

  prep_sigma<<<1, 256, 0, stream>>>(w, b, centers, ws, use_table);
  if (use_table)
    conv_vq_tab2<<<2 * (16 * HO * WO) / 256, 256, 0, stream>>>(x, w, ws, out);
  else
    conv_vq_exp<<<(16 * HO * WO) / 256, 256, 0, stream>>>(x, w, b, centers, ws, out);
}

// Round 5
// 42.374 us; speedup vs baseline: 3.0995x; 1.9348x over previous
//
#include <hip/hip_runtime.h>
#include <stdint.h>

#define CIN 3
#define WW 512
#define HW (512 * 512)
#define COUT 64
#define KF 48          // 3*4*4
#define HO 128
#define WO 128
#define LDA 52

#define NTAB 2048
#define YMIN (-12.0f)
#define YMAX (12.0f)
#define INVH ((float)NTAB / (YMAX - YMIN))   // 85.3333
// ws layout (floats): [0]=sigma, [1]=a=inv_sigma*INVH, [2..65]=o_c, [128..)=table(f0,df)
#define WS_TAB_OFF 128
#define WS_FLOATS (WS_TAB_OFF + 2 * NTAB)

typedef __attribute__((ext_vector_type(8))) short short8;
typedef __attribute__((ext_vector_type(4))) float f32x4;

union FragU { uint32_t u[4]; short8 s; };

__device__ __forceinline__ uint32_t pack_bf16_pair(float f0, float f1) {
  // bf16(f0) in low16 (truncation), bf16(f1) in high16
  return (__float_as_uint(f0) >> 16) | (__float_as_uint(f1) & 0xffff0000u);
}
__device__ __forceinline__ float trunc_bf16f(float f) {
  return __uint_as_float(__float_as_uint(f) & 0xffff0000u);
}
// hi = bf16_trunc(v), lo = bf16_trunc(v - hi); 8 elements = float4 pair (a,b)
__device__ __forceinline__ void split_pair(float4 a, float4 b, short8& hi, short8& lo) {
  FragU h, l;
  h.u[0] = pack_bf16_pair(a.x, a.y);
  h.u[1] = pack_bf16_pair(a.z, a.w);
  h.u[2] = pack_bf16_pair(b.x, b.y);
  h.u[3] = pack_bf16_pair(b.z, b.w);
  l.u[0] = pack_bf16_pair(a.x - trunc_bf16f(a.x), a.y - trunc_bf16f(a.y));
  l.u[1] = pack_bf16_pair(a.z - trunc_bf16f(a.z), a.w - trunc_bf16f(a.w));
  l.u[2] = pack_bf16_pair(b.x - trunc_bf16f(b.x), b.y - trunc_bf16f(b.y));
  l.u[3] = pack_bf16_pair(b.z - trunc_bf16f(b.z), b.w - trunc_bf16f(b.w));
  hi = h.s; lo = l.s;
}

// ---------------------------------------------------------------------------
// soft-VQ as a scalar function of y (centers fixed)
// ---------------------------------------------------------------------------
__device__ __forceinline__ float vq_eval(float y, const float* __restrict__ c) {
  float d[8], m;
#pragma unroll
  for (int k = 0; k < 8; ++k) { float t = y - c[k]; d[k] = t * t; }
  m = fminf(fminf(fminf(d[0], d[1]), fminf(d[2], d[3])),
            fminf(fminf(d[4], d[5]), fminf(d[6], d[7])));
  float num = 0.f, den = 0.f;
#pragma unroll
  for (int k = 0; k < 8; ++k) {
    float e = __expf(m - d[k]);
    den += e;
    num = fmaf(c[k], e, num);
  }
  return num / den;
}

// ---------------------------------------------------------------------------
// Kernel 1 (2 blocks): block 0 = sigma via G=W^T W, 4 squarings, 6 matvecs,
// Rayleigh; block 1 = VQ table + per-channel offsets (runs in parallel).
// ---------------------------------------------------------------------------
__global__ __launch_bounds__(256) void prep_sigma(
    const float* __restrict__ w, const float* __restrict__ bias,
    const float* __restrict__ centers, float* __restrict__ ws) {
  const int t = threadIdx.x;

  if (blockIdx.x == 1) {
    // ---- VQ table + per-channel offsets (independent of sigma) ----
    float c[8];
#pragma unroll
    for (int k = 0; k < 8; ++k) c[k] = centers[k];
    const float h = (YMAX - YMIN) / (float)NTAB;
#pragma unroll 1
    for (int k = t; k < NTAB; k += 256) {
      float y0 = YMIN + (float)k * h;
      float f0 = vq_eval(y0, c);
      float f1 = vq_eval(y0 + h, c);
      ws[WS_TAB_OFF + 2 * k]     = f0;
      ws[WS_TAB_OFF + 2 * k + 1] = f1 - f0;
    }
    if (t < COUT) ws[2 + t] = (bias[t] - YMIN) * INVH;
    return;
  }

  __shared__ float sW[COUT * KF];
  __shared__ float sG[KF * LDA];
  __shared__ float sA[KF * LDA];
  __shared__ float sB[KF * LDA];
  __shared__ float sv[64];
  __shared__ float sp[256];

  // ---- load W ----
  {
    const float4* w4 = (const float4*)w;
    float4* s4 = (float4*)sW;
#pragma unroll
    for (int q = 0; q < 3; ++q) s4[q * 256 + t] = w4[q * 256 + t];
  }
  __syncthreads();

  // ---- G = W^T W, 3x3 tile per thread ----
  const int ti = t >> 4, tj = t & 15;
  const int i0 = 3 * ti, j0 = 3 * tj;
  {
    float acc[3][3] = {{0.f}};
#pragma unroll 4
    for (int m = 0; m < COUT; ++m) {
      const float* wr = sW + m * KF;
      float a0 = wr[i0], a1 = wr[i0 + 1], a2 = wr[i0 + 2];
      float b0 = wr[j0], b1 = wr[j0 + 1], b2 = wr[j0 + 2];
      acc[0][0] = fmaf(a0, b0, acc[0][0]);
      acc[0][1] = fmaf(a0, b1, acc[0][1]);
      acc[0][2] = fmaf(a0, b2, acc[0][2]);
      acc[1][0] = fmaf(a1, b0, acc[1][0]);
      acc[1][1] = fmaf(a1, b1, acc[1][1]);
      acc[1][2] = fmaf(a1, b2, acc[1][2]);
      acc[2][0] = fmaf(a2, b0, acc[2][0]);
      acc[2][1] = fmaf(a2, b1, acc[2][1]);
      acc[2][2] = fmaf(a2, b2, acc[2][2]);
    }
#pragma unroll
    for (int ii = 0; ii < 3; ++ii)
#pragma unroll
      for (int jj = 0; jj < 3; ++jj) {
        sG[(i0 + ii) * LDA + j0 + jj] = acc[ii][jj];
        sA[(i0 + ii) * LDA + j0 + jj] = acc[ii][jj];
      }
  }
  __syncthreads();

  // ---- 4 squarings: G^16 ends in sA ----
#pragma unroll 1
  for (int s = 0; s < 4; ++s) {
    const float* src = (s & 1) ? sB : sA;
    float* dst = (s & 1) ? sA : sB;
    float acc[3][3] = {{0.f}};
#pragma unroll
    for (int q = 0; q < 12; ++q) {
      float4 ar0 = *(const float4*)(src + (i0 + 0) * LDA + 4 * q);
      float4 ar1 = *(const float4*)(src + (i0 + 1) * LDA + 4 * q);
      float4 ar2 = *(const float4*)(src + (i0 + 2) * LDA + 4 * q);
      float4 br0 = *(const float4*)(src + (j0 + 0) * LDA + 4 * q);
      float4 br1 = *(const float4*)(src + (j0 + 1) * LDA + 4 * q);
      float4 br2 = *(const float4*)(src + (j0 + 2) * LDA + 4 * q);
#define DOT4(A, B, C) \
      C = fmaf(A.x, B.x, C); C = fmaf(A.y, B.y, C); \
      C = fmaf(A.z, B.z, C); C = fmaf(A.w, B.w, C);
      DOT4(ar0, br0, acc[0][0]); DOT4(ar0, br1, acc[0][1]); DOT4(ar0, br2, acc[0][2]);
      DOT4(ar1, br0, acc[1][0]); DOT4(ar1, br1, acc[1][1]); DOT4(ar1, br2, acc[1][2]);
      DOT4(ar2, br0, acc[2][0]); DOT4(ar2, br1, acc[2][1]); DOT4(ar2, br2, acc[2][2]);
#undef DOT4
    }
    __syncthreads();
#pragma unroll
    for (int ii = 0; ii < 3; ++ii)
#pragma unroll
      for (int jj = 0; jj < 3; ++jj)
        dst[(i0 + ii) * LDA + j0 + jj] = acc[ii][jj];
    __syncthreads();
  }
  const float* M = sA;   // G^16

  if (t < 64) sv[t] = (t < KF) ? 1.0f : 0.f;
  __syncthreads();

  // ---- 6 matvecs ----
#pragma unroll 1
  for (int it = 0; it < 6; ++it) {
    float partial = 0.f;
    if (t < 192) {
      const int row = t >> 2, seg = t & 3;
      const float* mr = M + row * LDA + seg * 12;
      const float4* v4 = (const float4*)sv;
#pragma unroll
      for (int q = 0; q < 3; ++q) {
        float4 m4 = *(const float4*)(mr + 4 * q);
        float4 vv = v4[seg * 3 + q];
        partial = fmaf(m4.x, vv.x, partial);
        partial = fmaf(m4.y, vv.y, partial);
        partial = fmaf(m4.z, vv.z, partial);
        partial = fmaf(m4.w, vv.w, partial);
      }
    }
    sp[t] = partial;
    __syncthreads();
    if (t < 64) {
      float nv = 0.f;
      if (t < KF) nv = (sp[4 * t] + sp[4 * t + 1]) + (sp[4 * t + 2] + sp[4 * t + 3]);
      float ss = nv * nv;
#pragma unroll
      for (int m = 32; m >= 1; m >>= 1) ss += __shfl_xor(ss, m, 64);
      sv[t] = (t < KF) ? nv * rsqrtf(ss) : 0.f;
    }
    __syncthreads();
  }

  // ---- Rayleigh with original G ----
  {
    float partial = 0.f;
    if (t < 192) {
      const int row = t >> 2, seg = t & 3;
      const float* mr = sG + row * LDA + seg * 12;
      const float4* v4 = (const float4*)sv;
#pragma unroll
      for (int q = 0; q < 3; ++q) {
        float4 m4 = *(const float4*)(mr + 4 * q);
        float4 vv = v4[seg * 3 + q];
        partial = fmaf(m4.x, vv.x, partial);
        partial = fmaf(m4.y, vv.y, partial);
        partial = fmaf(m4.z, vv.z, partial);
        partial = fmaf(m4.w, vv.w, partial);
      }
    }
    sp[t] = partial;
    __syncthreads();
    if (t < 64) {
      float nv = 0.f;
      if (t < KF) nv = (sp[4 * t] + sp[4 * t + 1]) + (sp[4 * t + 2] + sp[4 * t + 3]);
      float vt = sv[t];
      float num = nv * vt;
      float den = vt * vt;
#pragma unroll
      for (int m = 32; m >= 1; m >>= 1) {
        num += __shfl_xor(num, m, 64);
        den += __shfl_xor(den, m, 64);
      }
      if (t == 0) {
        float sg = sqrtf(num / den);
        ws[0] = sg;
        ws[1] = INVH / sg;
      }
    }
  }
}

// ---------------------------------------------------------------------------
// Kernel 2: MFMA conv + table-VQ.
// C[64ch][N] = W[64x48] . P[48][N] via mfma_f32_16x16x32_bf16, hi/lo split.
// Because kernel==stride==4, a lane's B-fragment (8 consecutive k, 1 position)
// is exactly two contiguous float4 of x -> no im2col, x read exactly once.
// Block = 4 waves x 32 positions = 128 positions, all 64 channels.
// ---------------------------------------------------------------------------
__global__ __launch_bounds__(256) void conv_vq_mfma(
    const float* __restrict__ x, const float* __restrict__ w,
    const float* __restrict__ params, float* __restrict__ out) {
  __shared__ float stab[2 * NTAB];   // 16 KB (f0, df)
  __shared__ float so[COUT];
  const int t = threadIdx.x;
  {
    const float4* src = (const float4*)(params + WS_TAB_OFF);
    float4* dst = (float4*)stab;
#pragma unroll
    for (int q = 0; q < 4; ++q) dst[q * 256 + t] = src[q * 256 + t];
    if (t < COUT) so[t] = params[2 + t];
  }
  __syncthreads();

  const float a_scale = params[1];          // inv_sigma * INVH (scalar)

  const int lane = t & 63;
  const int wv   = t >> 6;
  const int g    = lane >> 4;               // k-group
  const int nl   = lane & 15;               // position-within-tile / A-row

  const int n0   = blockIdx.x * 128 + wv * 32;   // 16-aligned, same (b,i) for 32 pos
  const int b    = n0 >> 14;
  const int rem0 = n0 & 16383;
  const int i    = rem0 >> 7;
  const int j0   = rem0 & 127;

  const float* xb = x + (size_t)b * (CIN * HW) + (size_t)(4 * i) * WW;
  const short8 zfrag = {0, 0, 0, 0, 0, 0, 0, 0};

  // ---- B fragments: 2 sets of 16 positions, 2 K-steps, hi/lo ----
  // k = kk*32 + 8g + e ; k -> (ci,kh,kw) = (k/16, (k/4)&3, k&3)
  short8 Bh[2][2], Bl[2][2];
#pragma unroll
  for (int s = 0; s < 2; ++s) {
    const float* base = xb + 4 * (j0 + s * 16 + nl);
    {
      const int ci = g >> 1, kh = (g & 1) * 2;       // kk=0
      float4 fa = *(const float4*)(base + (size_t)ci * HW + kh * WW);
      float4 fb = *(const float4*)(base + (size_t)ci * HW + (kh + 1) * WW);
      split_pair(fa, fb, Bh[s][0], Bl[s][0]);
    }
    if (g < 2) {                                     // kk=1: k=32..47 (ci=2)
      const int kh = g * 2;
      float4 fa = *(const float4*)(base + (size_t)2 * HW + kh * WW);
      float4 fb = *(const float4*)(base + (size_t)2 * HW + (kh + 1) * WW);
      split_pair(fa, fb, Bh[s][1], Bl[s][1]);
    } else {                                         // k>=48 zero pad
      Bh[s][1] = zfrag; Bl[s][1] = zfrag;
    }
  }

  const float2* tab2 = (const float2*)stab;
  float* opb = out + (size_t)b * (COUT * 16384) + (size_t)(i * 128 + j0);

#pragma unroll 2
  for (int m = 0; m < 4; ++m) {
    // ---- A fragments for channel tile m: row = nl, k = kk*32 + 8g + e ----
    const float* wr = w + (size_t)(m * 16 + nl) * KF;
    short8 Ah[2], Al[2];
    {
      float4 fa = *(const float4*)(wr + 8 * g);
      float4 fb = *(const float4*)(wr + 8 * g + 4);
      split_pair(fa, fb, Ah[0], Al[0]);
    }
    if (g < 2) {
      float4 fa = *(const float4*)(wr + 32 + 8 * g);
      float4 fb = *(const float4*)(wr + 36 + 8 * g);
      split_pair(fa, fb, Ah[1], Al[1]);
    } else {
      Ah[1] = zfrag; Al[1] = zfrag;
    }

#pragma unroll
    for (int s = 0; s < 2; ++s) {
      f32x4 acc = {0.f, 0.f, 0.f, 0.f};
      acc = __builtin_amdgcn_mfma_f32_16x16x32_bf16(Ah[0], Bh[s][0], acc, 0, 0, 0);
      acc = __builtin_amdgcn_mfma_f32_16x16x32_bf16(Ah[1], Bh[s][1], acc, 0, 0, 0);
      acc = __builtin_amdgcn_mfma_f32_16x16x32_bf16(Ah[0], Bl[s][0], acc, 0, 0, 0);
      acc = __builtin_amdgcn_mfma_f32_16x16x32_bf16(Al[0], Bh[s][0], acc, 0, 0, 0);
      acc = __builtin_amdgcn_mfma_f32_16x16x32_bf16(Ah[1], Bl[s][1], acc, 0, 0, 0);
      acc = __builtin_amdgcn_mfma_f32_16x16x32_bf16(Al[1], Bh[s][1], acc, 0, 0, 0);

      // C/D: col(position) = lane&15, row(channel-in-tile) = 4*g + r
      float* op = opb + s * 16 + nl;
#pragma unroll
      for (int r = 0; r < 4; ++r) {
        const int ch = m * 16 + 4 * g + r;
        float u = fmaf(acc[r], a_scale, so[ch]);
        u = fmaxf(u, 0.0f);
        u = fminf(u, (float)NTAB - 0.0005f);
        const int k = (int)u;
        const float fr = u - (float)k;
        const float2 e = tab2[k];
        op[(size_t)ch * 16384] = fmaf(fr, e.y, e.x);
      }
    }
  }
}

// ---------------------------------------------------------------------------
// Fallback (exp path) — used only if ws is too small for the table.
// ---------------------------------------------------------------------------
__global__ __launch_bounds__(256) void conv_vq_exp(
    const float* __restrict__ x, const float* __restrict__ w,
    const float* __restrict__ bias, const float* __restrict__ centers,
    const float* __restrict__ sigma_ptr, float* __restrict__ out) {
  const int t = threadIdx.x;
  const int pos = blockIdx.x * 256 + t;
  const int b   = pos >> 14;
  const int rem = pos & 16383;
  const int i   = rem >> 7;
  const int j   = rem & 127;

  const float inv_sigma = 1.0f / sigma_ptr[0];
  float cc[8], tc[8], mc2[8];
#pragma unroll
  for (int k = 0; k < 8; ++k) {
    float c = centers[k];
    cc[k] = c; tc[k] = 2.0f * c; mc2[k] = -c * c;
  }
  const float* xp = x + (size_t)b * (CIN * HW) + (size_t)(4 * i) * WW + 4 * j;
  float p[KF];
#pragma unroll
  for (int ci = 0; ci < CIN; ++ci)
#pragma unroll
    for (int kh = 0; kh < 4; ++kh) {
      float4 v4 = *(const float4*)(xp + (size_t)ci * HW + kh * WW);
      p[(ci * 4 + kh) * 4 + 0] = v4.x;
      p[(ci * 4 + kh) * 4 + 1] = v4.y;
      p[(ci * 4 + kh) * 4 + 2] = v4.z;
      p[(ci * 4 + kh) * 4 + 3] = v4.w;
    }
  float* op = out + (size_t)b * (COUT * HO * WO) + rem;
#pragma unroll 2
  for (int c = 0; c < COUT; ++c) {
    const float4* wr = (const float4*)(w + c * KF);
    float a0 = 0.f, a1 = 0.f, a2 = 0.f, a3 = 0.f;
#pragma unroll
    for (int q = 0; q < 12; ++q) {
      float4 gq = wr[q];
      a0 = fmaf(p[4*q+0], gq.x, a0);
      a1 = fmaf(p[4*q+1], gq.y, a1);
      a2 = fmaf(p[4*q+2], gq.z, a2);
      a3 = fmaf(p[4*q+3], gq.w, a3);
    }
    const float y = fmaf((a0 + a1) + (a2 + a3), inv_sigma, bias[c]);
    float e0 = __expf(fmaf(tc[0], y, mc2[0])), e1 = __expf(fmaf(tc[1], y, mc2[1]));
    float e2 = __expf(fmaf(tc[2], y, mc2[2])), e3 = __expf(fmaf(tc[3], y, mc2[3]));
    float e4 = __expf(fmaf(tc[4], y, mc2[4])), e5 = __expf(fmaf(tc[5], y, mc2[5]));
    float e6 = __expf(fmaf(tc[6], y, mc2[6])), e7 = __expf(fmaf(tc[7], y, mc2[7]));
    float den = ((e0 + e1) + (e2 + e3)) + ((e4 + e5) + (e6 + e7));
    float num = (fmaf(cc[0], e0, cc[1] * e1) + fmaf(cc[2], e2, cc[3] * e3)) +
                (fmaf(cc[4], e4, cc[5] * e5) + fmaf(cc[6], e6, cc[7] * e7));
    op[(size_t)c * (HO * WO)] = __fdividef(num, den);
  }
}

extern "C" void kernel_launch(void* const* d_in, const int* in_sizes, int n_in,
                              void* d_out, int out_size, void* d_ws, size_t ws_size,
                              hipStream_t stream) {
  const float* x       = (const float*)d_in[0];
  const float* w       = (const float*)d_in[1];
  const float* b       = (const float*)d_in[2];
  const float* centers = (const float*)d_in[3];
  float* out = (float*)d_out;
  float* ws  = (float*)d_ws;

  const int use_table = (ws_size >= (size_t)WS_FLOATS * sizeof(float)) ? 1 : 0;

  prep_sigma<<<use_table ? 2 : 1, 256, 0, stream>>>(w, b, centers, ws);
  if (use_table)
    conv_vq_mfma<<<(16 * HO * WO) / 128, 256, 0, stream>>>(x, w, ws, out);
  else
    conv_vq_exp<<<(16 * HO * WO) / 256, 256, 0, stream>>>(x, w, b, centers, ws, out);
}

// Round 6
// 39.436 us; speedup vs baseline: 3.3304x; 1.0745x over previous
//
#include <hip/hip_runtime.h>
#include <stdint.h>

#define CIN 3
#define WW 512
#define HW (512 * 512)
#define COUT 64
#define KF 48          // 3*4*4
#define HO 128
#define WO 128
#define LDA 52

#define NTAB 2048
#define YMIN (-12.0f)
#define YMAX (12.0f)
#define INVH ((float)NTAB / (YMAX - YMIN))   // 85.3333
// ws layout (floats):
//   [0]=sigma, [1]=a=INVH/sigma, [2..65]=o_c (bias in table units)
//   [128 .. 128+4096)   = table (f0, df) pairs
//   [4352 .. 4352+1536) = W' hi fragments (bf16, MFMA A-order)
//   [5888 .. 5888+1536) = W' lo fragments
#define WS_TAB_OFF 128
#define WS_WP_HI 4352
#define WS_WP_LO 5888
#define WS_FLOATS (WS_WP_LO + 1536)

typedef __attribute__((ext_vector_type(8))) short short8;
typedef __attribute__((ext_vector_type(16))) float f32x16;

union FragU { uint32_t u[4]; short8 s; };

__device__ __forceinline__ uint32_t pack_bf16_pair(float f0, float f1) {
  return (__float_as_uint(f0) >> 16) | (__float_as_uint(f1) & 0xffff0000u);
}
__device__ __forceinline__ float trunc_bf16f(float f) {
  return __uint_as_float(__float_as_uint(f) & 0xffff0000u);
}
// hi = bf16_trunc(v), lo = bf16_trunc(v - hi); 8 elements = float4 pair (a,b)
__device__ __forceinline__ void split_pair(float4 a, float4 b, short8& hi, short8& lo) {
  FragU h, l;
  h.u[0] = pack_bf16_pair(a.x, a.y);
  h.u[1] = pack_bf16_pair(a.z, a.w);
  h.u[2] = pack_bf16_pair(b.x, b.y);
  h.u[3] = pack_bf16_pair(b.z, b.w);
  l.u[0] = pack_bf16_pair(a.x - trunc_bf16f(a.x), a.y - trunc_bf16f(a.y));
  l.u[1] = pack_bf16_pair(a.z - trunc_bf16f(a.z), a.w - trunc_bf16f(a.w));
  l.u[2] = pack_bf16_pair(b.x - trunc_bf16f(b.x), b.y - trunc_bf16f(b.y));
  l.u[3] = pack_bf16_pair(b.z - trunc_bf16f(b.z), b.w - trunc_bf16f(b.w));
  hi = h.s; lo = l.s;
}

__device__ __forceinline__ float vq_eval(float y, const float* __restrict__ c) {
  float d[8], m;
#pragma unroll
  for (int k = 0; k < 8; ++k) { float t = y - c[k]; d[k] = t * t; }
  m = fminf(fminf(fminf(d[0], d[1]), fminf(d[2], d[3])),
            fminf(fminf(d[4], d[5]), fminf(d[6], d[7])));
  float num = 0.f, den = 0.f;
#pragma unroll
  for (int k = 0; k < 8; ++k) {
    float e = __expf(m - d[k]);
    den += e;
    num = fmaf(c[k], e, num);
  }
  return num / den;
}

// ---------------------------------------------------------------------------
// Kernel 1 (2 blocks): block 1 = VQ table + per-channel offsets.
// block 0 = sigma (G=W^T W, 4 squarings, 6 matvecs, Rayleigh), then writes
// W' = W*(INVH/sigma) split to bf16 hi/lo in 32x32x16 MFMA A-fragment order.
// ---------------------------------------------------------------------------
__global__ __launch_bounds__(256) void prep_sigma(
    const float* __restrict__ w, const float* __restrict__ bias,
    const float* __restrict__ centers, float* __restrict__ ws, int build_tab) {
  const int t = threadIdx.x;

  if (blockIdx.x == 1) {
    float c[8];
#pragma unroll
    for (int k = 0; k < 8; ++k) c[k] = centers[k];
    const float h = (YMAX - YMIN) / (float)NTAB;
#pragma unroll 1
    for (int k = t; k < NTAB; k += 256) {
      float y0 = YMIN + (float)k * h;
      float f0 = vq_eval(y0, c);
      float f1 = vq_eval(y0 + h, c);
      ws[WS_TAB_OFF + 2 * k]     = f0;
      ws[WS_TAB_OFF + 2 * k + 1] = f1 - f0;
    }
    if (t < COUT) ws[2 + t] = (bias[t] - YMIN) * INVH;
    return;
  }

  __shared__ float sW[COUT * KF];
  __shared__ float sG[KF * LDA];
  __shared__ float sA[KF * LDA];
  __shared__ float sB[KF * LDA];
  __shared__ float sv[64];
  __shared__ float sp[256];
  __shared__ float s_a;

  {
    const float4* w4 = (const float4*)w;
    float4* s4 = (float4*)sW;
#pragma unroll
    for (int q = 0; q < 3; ++q) s4[q * 256 + t] = w4[q * 256 + t];
  }
  __syncthreads();

  const int ti = t >> 4, tj = t & 15;
  const int i0 = 3 * ti, j0 = 3 * tj;
  {
    float acc[3][3] = {{0.f}};
#pragma unroll 4
    for (int m = 0; m < COUT; ++m) {
      const float* wr = sW + m * KF;
      float a0 = wr[i0], a1 = wr[i0 + 1], a2 = wr[i0 + 2];
      float b0 = wr[j0], b1 = wr[j0 + 1], b2 = wr[j0 + 2];
      acc[0][0] = fmaf(a0, b0, acc[0][0]);
      acc[0][1] = fmaf(a0, b1, acc[0][1]);
      acc[0][2] = fmaf(a0, b2, acc[0][2]);
      acc[1][0] = fmaf(a1, b0, acc[1][0]);
      acc[1][1] = fmaf(a1, b1, acc[1][1]);
      acc[1][2] = fmaf(a1, b2, acc[1][2]);
      acc[2][0] = fmaf(a2, b0, acc[2][0]);
      acc[2][1] = fmaf(a2, b1, acc[2][1]);
      acc[2][2] = fmaf(a2, b2, acc[2][2]);
    }
#pragma unroll
    for (int ii = 0; ii < 3; ++ii)
#pragma unroll
      for (int jj = 0; jj < 3; ++jj) {
        sG[(i0 + ii) * LDA + j0 + jj] = acc[ii][jj];
        sA[(i0 + ii) * LDA + j0 + jj] = acc[ii][jj];
      }
  }
  __syncthreads();

#pragma unroll 1
  for (int s = 0; s < 4; ++s) {
    const float* src = (s & 1) ? sB : sA;
    float* dst = (s & 1) ? sA : sB;
    float acc[3][3] = {{0.f}};
#pragma unroll
    for (int q = 0; q < 12; ++q) {
      float4 ar0 = *(const float4*)(src + (i0 + 0) * LDA + 4 * q);
      float4 ar1 = *(const float4*)(src + (i0 + 1) * LDA + 4 * q);
      float4 ar2 = *(const float4*)(src + (i0 + 2) * LDA + 4 * q);
      float4 br0 = *(const float4*)(src + (j0 + 0) * LDA + 4 * q);
      float4 br1 = *(const float4*)(src + (j0 + 1) * LDA + 4 * q);
      float4 br2 = *(const float4*)(src + (j0 + 2) * LDA + 4 * q);
#define DOT4(A, B, C) \
      C = fmaf(A.x, B.x, C); C = fmaf(A.y, B.y, C); \
      C = fmaf(A.z, B.z, C); C = fmaf(A.w, B.w, C);
      DOT4(ar0, br0, acc[0][0]); DOT4(ar0, br1, acc[0][1]); DOT4(ar0, br2, acc[0][2]);
      DOT4(ar1, br0, acc[1][0]); DOT4(ar1, br1, acc[1][1]); DOT4(ar1, br2, acc[1][2]);
      DOT4(ar2, br0, acc[2][0]); DOT4(ar2, br1, acc[2][1]); DOT4(ar2, br2, acc[2][2]);
#undef DOT4
    }
    __syncthreads();
#pragma unroll
    for (int ii = 0; ii < 3; ++ii)
#pragma unroll
      for (int jj = 0; jj < 3; ++jj)
        dst[(i0 + ii) * LDA + j0 + jj] = acc[ii][jj];
    __syncthreads();
  }
  const float* M = sA;   // G^16

  if (t < 64) sv[t] = (t < KF) ? 1.0f : 0.f;
  __syncthreads();

#pragma unroll 1
  for (int it = 0; it < 6; ++it) {
    float partial = 0.f;
    if (t < 192) {
      const int row = t >> 2, seg = t & 3;
      const float* mr = M + row * LDA + seg * 12;
      const float4* v4 = (const float4*)sv;
#pragma unroll
      for (int q = 0; q < 3; ++q) {
        float4 m4 = *(const float4*)(mr + 4 * q);
        float4 vv = v4[seg * 3 + q];
        partial = fmaf(m4.x, vv.x, partial);
        partial = fmaf(m4.y, vv.y, partial);
        partial = fmaf(m4.z, vv.z, partial);
        partial = fmaf(m4.w, vv.w, partial);
      }
    }
    sp[t] = partial;
    __syncthreads();
    if (t < 64) {
      float nv = 0.f;
      if (t < KF) nv = (sp[4 * t] + sp[4 * t + 1]) + (sp[4 * t + 2] + sp[4 * t + 3]);
      float ss = nv * nv;
#pragma unroll
      for (int m = 32; m >= 1; m >>= 1) ss += __shfl_xor(ss, m, 64);
      sv[t] = (t < KF) ? nv * rsqrtf(ss) : 0.f;
    }
    __syncthreads();
  }

  {
    float partial = 0.f;
    if (t < 192) {
      const int row = t >> 2, seg = t & 3;
      const float* mr = sG + row * LDA + seg * 12;
      const float4* v4 = (const float4*)sv;
#pragma unroll
      for (int q = 0; q < 3; ++q) {
        float4 m4 = *(const float4*)(mr + 4 * q);
        float4 vv = v4[seg * 3 + q];
        partial = fmaf(m4.x, vv.x, partial);
        partial = fmaf(m4.y, vv.y, partial);
        partial = fmaf(m4.z, vv.z, partial);
        partial = fmaf(m4.w, vv.w, partial);
      }
    }
    sp[t] = partial;
    __syncthreads();
    if (t < 64) {
      float nv = 0.f;
      if (t < KF) nv = (sp[4 * t] + sp[4 * t + 1]) + (sp[4 * t + 2] + sp[4 * t + 3]);
      float vt = sv[t];
      float num = nv * vt;
      float den = vt * vt;
#pragma unroll
      for (int m = 32; m >= 1; m >>= 1) {
        num += __shfl_xor(num, m, 64);
        den += __shfl_xor(den, m, 64);
      }
      if (t == 0) {
        float sg = sqrtf(num / den);
        ws[0] = sg;
        ws[1] = INVH / sg;
        s_a = INVH / sg;
      }
    }
  }
  __syncthreads();

  // ---- W' fragments: slot = ct*192 + kk*64 + l ; row = 32ct + (l&31),
  //      kbase = 16kk + 8*(l>>5); 8 bf16 per slot (16 B) ----
  if (build_tab) {
    const float a = s_a;
#pragma unroll 1
    for (int slot = t; slot < 384; slot += 256) {
      const int ct = slot / 192;
      const int rm = slot % 192;
      const int kk = rm >> 6;
      const int l  = rm & 63;
      const int row = ct * 32 + (l & 31);
      const int kbase = kk * 16 + (l >> 5) * 8;
      const float* src = w + row * KF + kbase;
      float4 fa = *(const float4*)(src);
      float4 fb = *(const float4*)(src + 4);
      fa.x *= a; fa.y *= a; fa.z *= a; fa.w *= a;
      fb.x *= a; fb.y *= a; fb.z *= a; fb.w *= a;
      short8 hi, lo;
      split_pair(fa, fb, hi, lo);
      *(short8*)(ws + WS_WP_HI + slot * 4) = hi;
      *(short8*)(ws + WS_WP_LO + slot * 4) = lo;
    }
  }
}

// ---------------------------------------------------------------------------
// Kernel 2: 32x32x16 MFMA conv + table-VQ.
// Wave = 32 ch x 32 pos; block = 4 waves = 64 ch x 64 pos; grid = 4096.
// K=48 = 3 x K16 steps, no padding.  A (weights) preprocessed to bf16 hi/lo
// fragments by prep (scale folded in); bias enters via MFMA C-in.
// B (x): lane needs 8 consecutive k = two contiguous float4 -> no im2col.
// ---------------------------------------------------------------------------
__global__ __launch_bounds__(256) void conv_vq_mfma2(
    const float* __restrict__ x, const float* __restrict__ params,
    float* __restrict__ out) {
  __shared__ float stab[2 * NTAB];   // 16 KB (f0, df)
  __shared__ float sso[COUT];
  const int t = threadIdx.x;
  {
    const float4* src = (const float4*)(params + WS_TAB_OFF);
    float4* dst = (float4*)stab;
#pragma unroll
    for (int q = 0; q < 4; ++q) dst[q * 256 + t] = src[q * 256 + t];
    if (t < COUT) sso[t] = params[2 + t];
  }
  __syncthreads();

  const int lane = t & 63;
  const int wv   = t >> 6;
  const int ct   = wv & 1;                  // channel tile (32 ch)
  const int pt   = wv >> 1;                 // position tile (32 pos)
  const int h    = lane >> 5;               // k-half within lane group
  const int pl   = lane & 31;               // position-in-tile / A-row

  const int n0   = blockIdx.x * 64;         // 64-aligned: same (b,i) for block
  const int b    = n0 >> 14;
  const int rem0 = n0 & 16383;
  const int i    = rem0 >> 7;
  const int jj   = (rem0 & 127) + pt * 32 + pl;   // output column 0..127

  // ---- B fragments: kk-th needs rows kh=2h,2h+1 of channel ci=kk ----
  const float* xb = x + (size_t)b * (CIN * HW) + (size_t)(4 * i) * WW + 4 * jj;
  float4 xf[3][2];
#pragma unroll
  for (int kk = 0; kk < 3; ++kk) {
    xf[kk][0] = *(const float4*)(xb + (size_t)kk * HW + (2 * h) * WW);
    xf[kk][1] = *(const float4*)(xb + (size_t)kk * HW + (2 * h + 1) * WW);
  }
  short8 Bh[3], Bl[3];
#pragma unroll
  for (int kk = 0; kk < 3; ++kk) split_pair(xf[kk][0], xf[kk][1], Bh[kk], Bl[kk]);

  // ---- A fragments (preprocessed, L2-hot) ----
  const short8* AhP = (const short8*)(params + WS_WP_HI) + ct * 192 + lane;
  const short8* AlP = (const short8*)(params + WS_WP_LO) + ct * 192 + lane;
  short8 Ah[3], Al[3];
#pragma unroll
  for (int kk = 0; kk < 3; ++kk) { Ah[kk] = AhP[kk * 64]; Al[kk] = AlP[kk * 64]; }

  // ---- acc init = per-channel offset (bias folded, table units) ----
  // C/D: col = lane&31 (pos), row-in-tile = (r&3) + 8*(r>>2) + 4*h
  f32x16 acc;
  {
    const float* sob = sso + ct * 32 + 4 * h;
#pragma unroll
    for (int r = 0; r < 16; ++r) acc[r] = sob[(r & 3) + 8 * (r >> 2)];
  }

#pragma unroll
  for (int kk = 0; kk < 3; ++kk)
    acc = __builtin_amdgcn_mfma_f32_32x32x16_bf16(Ah[kk], Bh[kk], acc, 0, 0, 0);
#pragma unroll
  for (int kk = 0; kk < 3; ++kk) {
    acc = __builtin_amdgcn_mfma_f32_32x32x16_bf16(Ah[kk], Bl[kk], acc, 0, 0, 0);
    acc = __builtin_amdgcn_mfma_f32_32x32x16_bf16(Al[kk], Bh[kk], acc, 0, 0, 0);
  }

  // ---- epilogue: clamp, gather-lerp from LDS table, store ----
  const float2* tab2 = (const float2*)stab;
  float* ob = out + ((size_t)(b * COUT + ct * 32 + 4 * h)) * 16384 + i * 128 + jj;
#pragma unroll
  for (int r = 0; r < 16; ++r) {
    float u = acc[r];
    u = fmaxf(u, 0.0f);
    u = fminf(u, (float)NTAB - 0.0005f);
    const int k = (int)u;
    const float fr = u - (float)k;
    const float2 e = tab2[k];
    ob[(size_t)((r & 3) + 8 * (r >> 2)) * 16384] = fmaf(fr, e.y, e.x);
  }
}

// ---------------------------------------------------------------------------
// Fallback (exp path) — used only if ws is too small for the table.
// ---------------------------------------------------------------------------
__global__ __launch_bounds__(256) void conv_vq_exp(
    const float* __restrict__ x, const float* __restrict__ w,
    const float* __restrict__ bias, const float* __restrict__ centers,
    const float* __restrict__ sigma_ptr, float* __restrict__ out) {
  const int t = threadIdx.x;
  const int pos = blockIdx.x * 256 + t;
  const int b   = pos >> 14;
  const int rem = pos & 16383;
  const int i   = rem >> 7;
  const int j   = rem & 127;

  const float inv_sigma = 1.0f / sigma_ptr[0];
  float cc[8], tc[8], mc2[8];
#pragma unroll
  for (int k = 0; k < 8; ++k) {
    float c = centers[k];
    cc[k] = c; tc[k] = 2.0f * c; mc2[k] = -c * c;
  }
  const float* xp = x + (size_t)b * (CIN * HW) + (size_t)(4 * i) * WW + 4 * j;
  float p[KF];
#pragma unroll
  for (int ci = 0; ci < CIN; ++ci)
#pragma unroll
    for (int kh = 0; kh < 4; ++kh) {
      float4 v4 = *(const float4*)(xp + (size_t)ci * HW + kh * WW);
      p[(ci * 4 + kh) * 4 + 0] = v4.x;
      p[(ci * 4 + kh) * 4 + 1] = v4.y;
      p[(ci * 4 + kh) * 4 + 2] = v4.z;
      p[(ci * 4 + kh) * 4 + 3] = v4.w;
    }
  float* op = out + (size_t)b * (COUT * HO * WO) + rem;
#pragma unroll 2
  for (int c = 0; c < COUT; ++c) {
    const float4* wr = (const float4*)(w + c * KF);
    float a0 = 0.f, a1 = 0.f, a2 = 0.f, a3 = 0.f;
#pragma unroll
    for (int q = 0; q < 12; ++q) {
      float4 gq = wr[q];
      a0 = fmaf(p[4*q+0], gq.x, a0);
      a1 = fmaf(p[4*q+1], gq.y, a1);
      a2 = fmaf(p[4*q+2], gq.z, a2);
      a3 = fmaf(p[4*q+3], gq.w, a3);
    }
    const float y = fmaf((a0 + a1) + (a2 + a3), inv_sigma, bias[c]);
    float e0 = __expf(fmaf(tc[0], y, mc2[0])), e1 = __expf(fmaf(tc[1], y, mc2[1]));
    float e2 = __expf(fmaf(tc[2], y, mc2[2])), e3 = __expf(fmaf(tc[3], y, mc2[3]));
    float e4 = __expf(fmaf(tc[4], y, mc2[4])), e5 = __expf(fmaf(tc[5], y, mc2[5]));
    float e6 = __expf(fmaf(tc[6], y, mc2[6])), e7 = __expf(fmaf(tc[7], y, mc2[7]));
    float den = ((e0 + e1) + (e2 + e3)) + ((e4 + e5) + (e6 + e7));
    float num = (fmaf(cc[0], e0, cc[1] * e1) + fmaf(cc[2], e2, cc[3] * e3)) +
                (fmaf(cc[4], e4, cc[5] * e5) + fmaf(cc[6], e6, cc[7] * e7));
    op[(size_t)c * (HO * WO)] = __fdividef(num, den);
  }
}

extern "C" void kernel_launch(void* const* d_in, const int* in_sizes, int n_in,
                              void* d_out, int out_size, void* d_ws, size_t ws_size,
                              hipStream_t stream) {
  const float* x       = (const float*)d_in[0];
  const float* w       = (const float*)d_in[1];
  const float* b       = (const float*)d_in[2];
  const float* centers = (const float*)d_in[3];
  float* out = (float*)d_out;
  float* ws  = (float*)d_ws;

  const int use_table = (ws_size >= (size_t)WS_FLOATS * sizeof(float)) ? 1 : 0;

  prep_sigma<<<use_table ? 2 : 1, 256, 0, stream>>>(w, b, centers, ws, use_table);
  if (use_table)
    conv_vq_mfma2<<<(16 * HO * WO) / 64, 256, 0, stream>>>(x, ws, out);
  else
    conv_vq_exp<<<(16 * HO * WO) / 256, 256, 0, stream>>>(x, w, b, centers, ws, out);
}